// Round 11
// baseline (27.487 us; speedup 1.0000x reference)
//
#include <hip/hip_runtime.h>
#include <hip/hip_bf16.h>

#define BB 256
#define NGT 8
#define HWA 10647
#define NTH 1024
#define NREG 11          // ceil(HWA/NTH)
#define CAP 1024
#define NAB 96           // above-boundary count < k <= 72
#define HC 4             // histogram copies (salted by wave&3)
#define HP 264           // copy stride in ints: 264%32==8 -> copies 8 banks apart
#define EPSF 1e-6f
#define FP16_EPS 0.0009765625f

// exact reference value: -log1p(-clip(sigmoid(x)))
__device__ __forceinline__ float lv_exact(float x) {
    float s = 1.f / (1.f + expf(-x));
    s = fminf(fmaxf(s, EPSF), 1.f - EPSF);
    return -log1pf(-s);
}
// order-monotone unsigned key for float compare
__device__ __forceinline__ unsigned fkey(float x) {
    const unsigned u = __float_as_uint(x);
    return u ^ ((u & 0x80000000u) ? 0xFFFFFFFFu : 0x80000000u);
}

__global__ __launch_bounds__(NTH) void yolo_loss_fused(
    const float* __restrict__ pconf, const float* __restrict__ pcls,
    const float* __restrict__ ptxywh, const float* __restrict__ gboxes,
    const int* __restrict__ glabels, float* __restrict__ partial,
    unsigned* __restrict__ counter, float* __restrict__ out)
{
    const int b = blockIdx.x;
    const int tid = threadIdx.x;
    const int lane = tid & 63;
    const int wv = tid >> 6;

    __shared__ int   hist[HC][HP];       // salted histogram, copies bank-offset
    __shared__ int   hist2[256];
    __shared__ __align__(16) float cand[CAP];
    __shared__ float sab[NAB];
    __shared__ int   s_idx[NGT];
    __shared__ float s_row[NGT][13];
    __shared__ int   s_npos, s_ccount, s_nab, s_b, s_above, s_m, s_cbin, s_last;
    __shared__ int   wtot[4];
    __shared__ float fred[16];

    // snapshot arrival counter first (all 256 blocks co-resident: 1 block/CU)
    unsigned snap = 0;
    if (tid == 0)
        snap = __hip_atomic_load(counter, __ATOMIC_RELAXED, __HIP_MEMORY_SCOPE_AGENT);

    // ---- issue all global loads early ----
    float gl = 0.f, gt = 0.f, gr = 0.f, gbo = 0.f;
    int lab = 0;
    if (tid < NGT) {
        const float* gb = gboxes + ((size_t)b * NGT + tid) * 4;
        gl = gb[0]; gt = gb[1]; gr = gb[2]; gbo = gb[3];
        lab = glabels[b * NGT + tid] - 1;
    }
    const float* pc = pconf + (size_t)b * HWA;
    float x[NREG];
#pragma unroll
    for (int v = 0; v < NREG; ++v) {
        const int p = tid + v * NTH;
        x[v] = (p < HWA) ? pc[p] : 0.f;
    }
    for (int i = tid; i < HC * HP; i += NTH) ((int*)hist)[i] = 0;
    if (tid < 256) hist2[tid] = 0;
    if (tid == 0)  { s_npos = 0; s_ccount = 0; s_nab = 0; }

    // ---- Phase A: per-GT matching (threads 0..7) ----
    if (tid < NGT) {
        const float cx = (gl + gr) * 0.5f, cy = (gt + gbo) * 0.5f;
        const float w = gr - gl, h = gbo - gt;
        const float area_g = w * h;
        const float AW[9] = {0.0276f, 0.0386f, 0.0795f, 0.0721f, 0.1495f, 0.1421f, 0.2788f, 0.375f, 0.897f};
        const float AH[9] = {0.0361f, 0.0697f, 0.0553f, 0.1466f, 0.1087f, 0.2861f, 0.2163f, 0.476f, 0.784f};
        float best = -1.f, baw = AW[0], bah = AH[0];
        int id = 0;
#pragma unroll
        for (int a = 0; a < 9; ++a) {
            float inter = fminf(w, AW[a]) * fminf(h, AH[a]);
            float iou = inter / (area_g + AW[a] * AH[a] - inter);
            if (iou > best) { best = iou; id = a; baw = AW[a]; bah = AH[a]; }
        }
        const int ceng = id / 3, anc = id % 3;
        const int grid = (ceng == 0) ? 52 : ((ceng == 1) ? 26 : 13);
        const int coff = (ceng == 0) ? 0 : ((ceng == 1) ? 8112 : 10140);
        const float gf = (float)grid;
        const int col = (int)(cx * gf);
        const int row = (int)(cy * gf);
        s_idx[tid] = coff + (row * grid + col) * 3 + anc;
        float* rr = s_row[tid];
        rr[0] = 1.f;
        rr[1] = (lab == 0) ? 1.f : 0.f;
        rr[2] = (lab == 1) ? 1.f : 0.f;
        rr[3] = (lab == 2) ? 1.f : 0.f;
        rr[4] = (cx - (float)col / gf) * gf;
        rr[5] = (cy - (float)row / gf) * gf;
        rr[6] = logf(w / baw);
        rr[7] = logf(h / bah);
        rr[8] = 2.f - area_g;
        rr[9] = gl; rr[10] = gt; rr[11] = gr; rr[12] = gbo;
    }
    __syncthreads();   // B1: s_idx/s_row ready, hists zeroed

    // hoist match indices to registers (broadcast LDS reads)
    int idxr[NGT];
#pragma unroll
    for (int j = 0; j < NGT; ++j) idxr[j] = s_idx[j];

    float psum = 0.f;  // this thread's share of every loss term

    // ---- Phase A2: scatter replay on threads 0..23 ----
    int myconf = 0, mysrc = -1, myp = -1; bool canon = false;
    if (tid < 3 * NGT) {
        const int i = tid / 3, d = tid % 3;
        const int p = idxr[i] + d;
        if (p < HWA) {                    // OOB scatter dropped by JAX
            myp = p;
            canon = true;
            for (int c2 = 0; c2 < tid; ++c2)
                if (idxr[c2 / 3] + (c2 % 3) == p) { canon = false; break; }
#pragma unroll
            for (int j = 0; j < NGT; ++j) {
                const int dj = p - idxr[j];
                if (dj >= 0 && dj < 3) myconf = -1;     // ignore-mark col0
                if (dj == 0) { myconf = 1; mysrc = j; } // full-row set
            }
            if (canon && myconf == 1) atomicAdd(&s_npos, 1);
        }
    }

    // ---- Phase D: positive-position terms (≤24 lanes; independent of hist) ----
    if (canon && myconf == 1) {
        const float* rr = s_row[mysrc];
        const int p = myp;
        float acc = -logf(fminf(fmaxf(1.f / (1.f + expf(-pc[p])), EPSF), 1.f - EPSF));
        const float* pcl = pcls + ((size_t)b * HWA + p) * 3;
#pragma unroll
        for (int cc = 0; cc < 3; ++cc) {
            const float sc = fminf(fmaxf(1.f / (1.f + expf(-pcl[cc])), EPSF), 1.f - EPSF);
            const float g = rr[1 + cc];
            acc += -(g * logf(sc) + (1.f - g) * log1pf(-sc));
        }
        const float* pt = ptxywh + ((size_t)b * HWA + p) * 4;
        const float wgt = rr[8];
        float a2 = 0.f;
#pragma unroll
        for (int cc = 0; cc < 2; ++cc) {
            const float st = fminf(fmaxf(1.f / (1.f + expf(-pt[cc])), EPSF), 1.f - EPSF);
            const float g = rr[4 + cc];
            a2 += -(g * logf(st) + (1.f - g) * log1pf(-st));
        }
        acc += a2 * wgt;
        const float d0 = pt[2] - rr[6], d1 = pt[3] - rr[7];
        acc += (d0 * d0 + d1 * d1) * wgt;
        psum += acc;
    }

    // ---- Phase B: mask (incremental compare) + salted key histogram ----
    int cj[NGT];
#pragma unroll
    for (int j = 0; j < NGT; ++j) cj[j] = tid - idxr[j];
    unsigned mmask = 0;
#pragma unroll
    for (int v = 0; v < NREG; ++v) {
        const int p = tid + v * NTH;
        bool m = (p >= HWA);
#pragma unroll
        for (int j = 0; j < NGT; ++j) m = m || ((unsigned)cj[j] < 3u);
        if (m) mmask |= (1u << v);
        else atomicAdd(&hist[wv & (HC - 1)][fkey(x[v]) >> 24], 1);
#pragma unroll
        for (int j = 0; j < NGT; ++j) cj[j] += NTH;
    }
    __syncthreads();   // B2: hist + npos final

    const int npos = s_npos;
    const float nums_pos = fmaxf((float)npos, FP16_EPS);
    const int k = (npos > 0) ? (3 * npos) : 1;

    // ---- boundary-byte search: fold copies + parallel suffix scan ----
    int hv = 0, sfx = 0;
    if (tid < 256) {
#pragma unroll
        for (int c = 0; c < HC; ++c) hv += hist[c][tid];
        sfx = hv;
#pragma unroll
        for (int off = 1; off < 64; off <<= 1) {
            const int o = __shfl_down(sfx, off, 64);
            sfx += (lane + off < 64) ? o : 0;
        }
        if (lane == 0) wtot[tid >> 6] = sfx;
    }
    __syncthreads();   // B3
    if (tid < 256) {
        const int w = tid >> 6;
        for (int w2 = w + 1; w2 < 4; ++w2) sfx += wtot[w2];
        const int above = sfx - hv;
        if (above < k && above + hv >= k) { s_b = tid; s_above = above; s_cbin = hv; }
    }
    __syncthreads();   // B4: s_b, s_above, s_cbin known

    const int bStar = s_b;
    const bool fits = (s_cbin <= CAP);

    // ---- gather above-boundary + boundary-bin from registers ----
#pragma unroll
    for (int v = 0; v < NREG; ++v) {
        if (!(mmask & (1u << v))) {
            const unsigned kb = fkey(x[v]) >> 24;
            if ((int)kb > bStar) {
                const int i = atomicAdd(&s_nab, 1);
                sab[i] = x[v];
            } else if ((int)kb == bStar) {
                if (fits) { const int c = atomicAdd(&s_ccount, 1); cand[c] = x[v]; }
                else atomicAdd(&hist2[(fkey(x[v]) >> 16) & 0xff], 1);
            }
        }
    }
    __syncthreads();   // B5: sab/cand (or hist2) ready

    // compacted libm for above-boundary values
    for (int t = tid; t < s_nab; t += NTH) psum += lv_exact(sab[t]);

    int rneed;
    if (fits) {
        rneed = k - s_above;
    } else {
        // rare fallback: refine by next 8 key bits
        int hv2 = 0, sfx2 = 0;
        if (tid < 256) {
            hv2 = hist2[tid];
            sfx2 = hv2;
#pragma unroll
            for (int off = 1; off < 64; off <<= 1) {
                const int o = __shfl_down(sfx2, off, 64);
                sfx2 += (lane + off < 64) ? o : 0;
            }
            if (lane == 0) wtot[tid >> 6] = sfx2;
        }
        __syncthreads();
        if (tid < 256) {
            const int w = tid >> 6;
            for (int w2 = w + 1; w2 < 4; ++w2) sfx2 += wtot[w2];
            const int above2 = s_above + (sfx2 - hv2);
            if (above2 < k && above2 + hv2 >= k) { s_m = tid; s_above = above2; }
        }
        __syncthreads();
        const int mStar = s_m;
#pragma unroll
        for (int v = 0; v < NREG; ++v) {
            if (!(mmask & (1u << v))) {
                const unsigned kk = fkey(x[v]);
                if ((int)(kk >> 24) == bStar) {
                    const int mb = (int)((kk >> 16) & 0xff);
                    if (mb > mStar) psum += lv_exact(x[v]);
                    else if (mb == mStar) {
                        const int c = atomicAdd(&s_ccount, 1);
                        if (c < CAP) cand[c] = x[v];
                    }
                }
            }
        }
        __syncthreads();
        rneed = k - s_above;
    }

    // ---- one-shot rank select over boundary candidates (float4 LDS reads) ----
    const int C = min(s_ccount, CAP);
    const int C4 = C & ~3;
    for (int t = tid; t < C; t += NTH) {
        const float v = cand[t];
        int rank = 0;
        for (int j = 0; j < C4; j += 4) {
            const float4 w4 = *reinterpret_cast<const float4*>(&cand[j]);
            rank += (w4.x > v) || (w4.x == v && (j + 0) < t);
            rank += (w4.y > v) || (w4.y == v && (j + 1) < t);
            rank += (w4.z > v) || (w4.z == v && (j + 2) < t);
            rank += (w4.w > v) || (w4.w == v && (j + 3) < t);
        }
        for (int j = C4; j < C; ++j) {
            const float w = cand[j];
            rank += (w > v) || (w == v && j < t);
        }
        if (rank < rneed) psum += lv_exact(v);
    }

    // ---- deterministic block reduction ----
    {
        float v = psum;
#pragma unroll
        for (int off = 32; off > 0; off >>= 1) v += __shfl_down(v, off, 64);
        if (lane == 0) fred[wv] = v;
    }
    __syncthreads();   // B6
    if (tid == 0) {
        float t = 0.f;
#pragma unroll
        for (int w = 0; w < 16; ++w) t += fred[w];
        __hip_atomic_store(&partial[b], t / nums_pos,
                           __ATOMIC_RELEASE, __HIP_MEMORY_SCOPE_AGENT);
        // snapshot last-arrival (base-independent, no reset node needed):
        // all snapshots precede any increment (blocks co-resident), so old
        // values this call are {base..base+255} and exactly old==snap+255
        // triggers; a late snapshot could only yield NO trigger (out keeps
        // the previous replay's value, identical for identical inputs).
        const unsigned old = __hip_atomic_fetch_add(counter, 1u,
                           __ATOMIC_ACQ_REL, __HIP_MEMORY_SCOPE_AGENT);
        s_last = (old == snap + 255u) ? 1 : 0;
    }
    __syncthreads();   // B7: s_last visible

    // ---- last-arriving block: fixed-order final reduction (bit-deterministic) ----
    if (s_last) {
        float v = 0.f;
        if (tid < BB)
            v = __hip_atomic_load(&partial[tid], __ATOMIC_ACQUIRE,
                                  __HIP_MEMORY_SCOPE_AGENT);
#pragma unroll
        for (int off = 32; off > 0; off >>= 1) v += __shfl_down(v, off, 64);
        if (lane == 0) fred[wv] = v;
        __syncthreads();
        if (tid == 0) {
            float s = 0.f;
#pragma unroll
            for (int w = 0; w < 16; ++w) s += fred[w];
            out[0] = s * (1.f / (float)BB);
        }
    }
}

extern "C" void kernel_launch(void* const* d_in, const int* in_sizes, int n_in,
                              void* d_out, int out_size, void* d_ws, size_t ws_size,
                              hipStream_t stream) {
    const float* pconf   = (const float*)d_in[0];
    const float* pcls    = (const float*)d_in[1];
    const float* ptxywh  = (const float*)d_in[2];
    const float* gboxes  = (const float*)d_in[3];
    const int*   glabels = (const int*)d_in[4];
    float* out = (float*)d_out;
    float* partial = (float*)d_ws;                         // 256 floats
    unsigned* counter = (unsigned*)((char*)d_ws + 1024);   // 1 u32 (never reset)

    yolo_loss_fused<<<BB, NTH, 0, stream>>>(pconf, pcls, ptxywh, gboxes,
                                            glabels, partial, counter, out);
}

// Round 12
// 25.787 us; speedup vs baseline: 1.0659x; 1.0659x over previous
//
#include <hip/hip_runtime.h>
#include <hip/hip_bf16.h>

#define BB 256
#define NGT 8
#define HWA 10647
#define NTH 1024
#define NREG 11          // ceil(HWA/NTH)
#define CAP 1024
#define NAB 96           // above-boundary count < k <= 72
#define EPSF 1e-6f
#define FP16_EPS 0.0009765625f

// exact reference value: -log1p(-clip(sigmoid(x)))
__device__ __forceinline__ float lv_exact(float x) {
    float s = 1.f / (1.f + expf(-x));
    s = fminf(fmaxf(s, EPSF), 1.f - EPSF);
    return -log1pf(-s);
}
// order-monotone unsigned key for float compare
__device__ __forceinline__ unsigned fkey(float x) {
    const unsigned u = __float_as_uint(x);
    return u ^ ((u & 0x80000000u) ? 0xFFFFFFFFu : 0x80000000u);
}

__global__ __launch_bounds__(NTH) void yolo_loss_batch(
    const float* __restrict__ pconf, const float* __restrict__ pcls,
    const float* __restrict__ ptxywh, const float* __restrict__ gboxes,
    const int* __restrict__ glabels, float* __restrict__ partial)
{
    const int b = blockIdx.x;
    const int tid = threadIdx.x;
    const int lane = tid & 63;

    __shared__ int   hist[256];
    __shared__ int   hist2[256];
    __shared__ __align__(16) float cand[CAP];
    __shared__ float sab[NAB];
    __shared__ int   s_idx[NGT];
    __shared__ float s_row[NGT][13];
    __shared__ int   s_npos, s_ccount, s_nab;
    __shared__ float fred[16];

    // ---- issue all global loads early ----
    float gl = 0.f, gt = 0.f, gr = 0.f, gbo = 0.f;
    int lab = 0;
    if (tid < NGT) {
        const float* gb = gboxes + ((size_t)b * NGT + tid) * 4;
        gl = gb[0]; gt = gb[1]; gr = gb[2]; gbo = gb[3];
        lab = glabels[b * NGT + tid] - 1;
    }
    const float* pc = pconf + (size_t)b * HWA;
    float x[NREG];
#pragma unroll
    for (int v = 0; v < NREG; ++v) {
        const int p = tid + v * NTH;
        x[v] = (p < HWA) ? pc[p] : 0.f;
    }
    if (tid < 256) { hist[tid] = 0; hist2[tid] = 0; }
    if (tid == 0)  { s_npos = 0; s_ccount = 0; s_nab = 0; }

    // ---- Phase A: per-GT matching (threads 0..7) ----
    if (tid < NGT) {
        const float cx = (gl + gr) * 0.5f, cy = (gt + gbo) * 0.5f;
        const float w = gr - gl, h = gbo - gt;
        const float area_g = w * h;
        const float AW[9] = {0.0276f, 0.0386f, 0.0795f, 0.0721f, 0.1495f, 0.1421f, 0.2788f, 0.375f, 0.897f};
        const float AH[9] = {0.0361f, 0.0697f, 0.0553f, 0.1466f, 0.1087f, 0.2861f, 0.2163f, 0.476f, 0.784f};
        float best = -1.f, baw = AW[0], bah = AH[0];
        int id = 0;
#pragma unroll
        for (int a = 0; a < 9; ++a) {
            float inter = fminf(w, AW[a]) * fminf(h, AH[a]);
            float iou = inter / (area_g + AW[a] * AH[a] - inter);
            if (iou > best) { best = iou; id = a; baw = AW[a]; bah = AH[a]; }
        }
        const int ceng = id / 3, anc = id % 3;
        const int grid = (ceng == 0) ? 52 : ((ceng == 1) ? 26 : 13);
        const int coff = (ceng == 0) ? 0 : ((ceng == 1) ? 8112 : 10140);
        const float gf = (float)grid;
        const int col = (int)(cx * gf);
        const int row = (int)(cy * gf);
        s_idx[tid] = coff + (row * grid + col) * 3 + anc;
        float* rr = s_row[tid];
        rr[0] = 1.f;
        rr[1] = (lab == 0) ? 1.f : 0.f;
        rr[2] = (lab == 1) ? 1.f : 0.f;
        rr[3] = (lab == 2) ? 1.f : 0.f;
        rr[4] = (cx - (float)col / gf) * gf;
        rr[5] = (cy - (float)row / gf) * gf;
        rr[6] = logf(w / baw);
        rr[7] = logf(h / bah);
        rr[8] = 2.f - area_g;
        rr[9] = gl; rr[10] = gt; rr[11] = gr; rr[12] = gbo;
    }
    __syncthreads();   // B1: s_idx/s_row ready, hists zeroed

    // hoist match indices to registers (broadcast LDS reads)
    int idxr[NGT];
#pragma unroll
    for (int j = 0; j < NGT; ++j) idxr[j] = s_idx[j];

    float psum = 0.f;  // this thread's share of every loss term

    // ---- Phase A2: scatter replay on threads 0..23 ----
    int myconf = 0, mysrc = -1, myp = -1; bool canon = false;
    if (tid < 3 * NGT) {
        const int i = tid / 3, d = tid % 3;
        const int p = idxr[i] + d;
        if (p < HWA) {                    // OOB scatter dropped by JAX
            myp = p;
            canon = true;
            for (int c2 = 0; c2 < tid; ++c2)
                if (idxr[c2 / 3] + (c2 % 3) == p) { canon = false; break; }
#pragma unroll
            for (int j = 0; j < NGT; ++j) {
                const int dj = p - idxr[j];
                if (dj >= 0 && dj < 3) myconf = -1;     // ignore-mark col0
                if (dj == 0) { myconf = 1; mysrc = j; } // full-row set
            }
            if (canon && myconf == 1) atomicAdd(&s_npos, 1);
        }
    }

    // ---- Phase D: positive-position terms (≤24 lanes; independent of hist) ----
    if (canon && myconf == 1) {
        const float* rr = s_row[mysrc];
        const int p = myp;
        float acc = -logf(fminf(fmaxf(1.f / (1.f + expf(-pc[p])), EPSF), 1.f - EPSF));
        const float* pcl = pcls + ((size_t)b * HWA + p) * 3;
#pragma unroll
        for (int cc = 0; cc < 3; ++cc) {
            const float sc = fminf(fmaxf(1.f / (1.f + expf(-pcl[cc])), EPSF), 1.f - EPSF);
            const float g = rr[1 + cc];
            acc += -(g * logf(sc) + (1.f - g) * log1pf(-sc));
        }
        const float* pt = ptxywh + ((size_t)b * HWA + p) * 4;
        const float wgt = rr[8];
        float a2 = 0.f;
#pragma unroll
        for (int cc = 0; cc < 2; ++cc) {
            const float st = fminf(fmaxf(1.f / (1.f + expf(-pt[cc])), EPSF), 1.f - EPSF);
            const float g = rr[4 + cc];
            a2 += -(g * logf(st) + (1.f - g) * log1pf(-st));
        }
        acc += a2 * wgt;
        const float d0 = pt[2] - rr[6], d1 = pt[3] - rr[7];
        acc += (d0 * d0 + d1 * d1) * wgt;
        psum += acc;
    }

    // ---- Phase B: mask (incremental compare) + key histogram ----
    int cj[NGT];
#pragma unroll
    for (int j = 0; j < NGT; ++j) cj[j] = tid - idxr[j];
    unsigned mmask = 0;
#pragma unroll
    for (int v = 0; v < NREG; ++v) {
        const int p = tid + v * NTH;
        bool m = (p >= HWA);
#pragma unroll
        for (int j = 0; j < NGT; ++j) m = m || ((unsigned)cj[j] < 3u);
        if (m) mmask |= (1u << v);
        else atomicAdd(&hist[fkey(x[v]) >> 24], 1);
#pragma unroll
        for (int j = 0; j < NGT; ++j) cj[j] += NTH;
    }
    __syncthreads();   // B2: hist + npos final

    const int npos = s_npos;
    const float nums_pos = fmaxf((float)npos, FP16_EPS);
    const int k = (npos > 0) ? (3 * npos) : 1;

    // ---- boundary-byte search: replicated per-wave suffix scan (no barriers) ----
    int bStar, above1, cbin;
    {
        const int h0 = hist[4 * lane + 0], h1 = hist[4 * lane + 1];
        const int h2 = hist[4 * lane + 2], h3 = hist[4 * lane + 3];
        const int s3 = h3, s2 = h2 + s3, s1 = h1 + s2, s0 = h0 + s1;
        int t = s0;
#pragma unroll
        for (int off = 1; off < 64; off <<= 1) {
            const int o = __shfl_down(t, off, 64);
            t += (lane + off < 64) ? o : 0;
        }
        const int aw = t - s0;              // count in lanes > lane
        int fbin = 0, fsa = 0, fcb = 0;
        bool found = false;
        const int a0 = aw + s1, a1 = aw + s2, a2 = aw + s3, a3 = aw;
        if (a0 < k && a0 + h0 >= k) { fbin = 4 * lane + 0; fsa = a0; fcb = h0; found = true; }
        if (a1 < k && a1 + h1 >= k) { fbin = 4 * lane + 1; fsa = a1; fcb = h1; found = true; }
        if (a2 < k && a2 + h2 >= k) { fbin = 4 * lane + 2; fsa = a2; fcb = h2; found = true; }
        if (a3 < k && a3 + h3 >= k) { fbin = 4 * lane + 3; fsa = a3; fcb = h3; found = true; }
        const unsigned long long bm = __ballot(found);
        const int src = __ffsll(bm) - 1;
        bStar  = __shfl(fbin, src, 64);
        above1 = __shfl(fsa,  src, 64);
        cbin   = __shfl(fcb,  src, 64);
    }
    const bool fits = (cbin <= CAP);

    // ---- gather above-boundary + boundary-bin from registers ----
#pragma unroll
    for (int v = 0; v < NREG; ++v) {
        if (!(mmask & (1u << v))) {
            const unsigned kb = fkey(x[v]) >> 24;
            if ((int)kb > bStar) {
                const int i = atomicAdd(&s_nab, 1);
                sab[i] = x[v];
            } else if ((int)kb == bStar) {
                if (fits) { const int c = atomicAdd(&s_ccount, 1); cand[c] = x[v]; }
                else atomicAdd(&hist2[(fkey(x[v]) >> 16) & 0xff], 1);
            }
        }
    }
    __syncthreads();   // B5: sab/cand (or hist2) ready

    // compacted libm for above-boundary values
    for (int t = tid; t < s_nab; t += NTH) psum += lv_exact(sab[t]);

    int rneed;
    if (fits) {
        rneed = k - above1;
    } else {
        // rare fallback: refine by next 8 key bits (replicated wave scan)
        int mStar, aboveF;
        {
            const int h0 = hist2[4 * lane + 0], h1 = hist2[4 * lane + 1];
            const int h2 = hist2[4 * lane + 2], h3 = hist2[4 * lane + 3];
            const int s3 = h3, s2 = h2 + s3, s1 = h1 + s2, s0 = h0 + s1;
            int t = s0;
#pragma unroll
            for (int off = 1; off < 64; off <<= 1) {
                const int o = __shfl_down(t, off, 64);
                t += (lane + off < 64) ? o : 0;
            }
            const int aw = t - s0;
            int fbin = 0, fsa = 0;
            bool found = false;
            const int a0 = above1 + aw + s1, a1 = above1 + aw + s2;
            const int a2 = above1 + aw + s3, a3 = above1 + aw;
            if (a0 < k && a0 + h0 >= k) { fbin = 4 * lane + 0; fsa = a0; found = true; }
            if (a1 < k && a1 + h1 >= k) { fbin = 4 * lane + 1; fsa = a1; found = true; }
            if (a2 < k && a2 + h2 >= k) { fbin = 4 * lane + 2; fsa = a2; found = true; }
            if (a3 < k && a3 + h3 >= k) { fbin = 4 * lane + 3; fsa = a3; found = true; }
            const unsigned long long bm = __ballot(found);
            const int src = __ffsll(bm) - 1;
            mStar  = __shfl(fbin, src, 64);
            aboveF = __shfl(fsa,  src, 64);
        }
#pragma unroll
        for (int v = 0; v < NREG; ++v) {
            if (!(mmask & (1u << v))) {
                const unsigned kk = fkey(x[v]);
                if ((int)(kk >> 24) == bStar) {
                    const int mb = (int)((kk >> 16) & 0xff);
                    if (mb > mStar) psum += lv_exact(x[v]);
                    else if (mb == mStar) {
                        const int c = atomicAdd(&s_ccount, 1);
                        if (c < CAP) cand[c] = x[v];
                    }
                }
            }
        }
        __syncthreads();
        rneed = k - aboveF;
    }

    // ---- one-shot rank select over boundary candidates (float4 LDS reads) ----
    const int C = min(s_ccount, CAP);
    const int C4 = C & ~3;
    for (int t = tid; t < C; t += NTH) {
        const float v = cand[t];
        int rank = 0;
        for (int j = 0; j < C4; j += 4) {
            const float4 w4 = *reinterpret_cast<const float4*>(&cand[j]);
            rank += (w4.x > v) || (w4.x == v && (j + 0) < t);
            rank += (w4.y > v) || (w4.y == v && (j + 1) < t);
            rank += (w4.z > v) || (w4.z == v && (j + 2) < t);
            rank += (w4.w > v) || (w4.w == v && (j + 3) < t);
        }
        for (int j = C4; j < C; ++j) {
            const float w = cand[j];
            rank += (w > v) || (w == v && j < t);
        }
        if (rank < rneed) psum += lv_exact(v);
    }

    // ---- deterministic block reduction ----
    {
        float v = psum;
#pragma unroll
        for (int off = 32; off > 0; off >>= 1) v += __shfl_down(v, off, 64);
        if (lane == 0) fred[tid >> 6] = v;
    }
    __syncthreads();
    if (tid == 0) {
        float t = 0.f;
#pragma unroll
        for (int w = 0; w < 16; ++w) t += fred[w];
        partial[b] = t / nums_pos;
    }
}

__global__ __launch_bounds__(256) void yolo_loss_reduce(
    const float* __restrict__ partial, float* __restrict__ out)
{
    const int tid = threadIdx.x;
    float v = partial[tid];
#pragma unroll
    for (int off = 32; off > 0; off >>= 1) v += __shfl_down(v, off, 64);
    __shared__ float s[4];
    if ((tid & 63) == 0) s[tid >> 6] = v;
    __syncthreads();
    if (tid == 0) out[0] = (s[0] + s[1] + s[2] + s[3]) * (1.f / (float)BB);
}

extern "C" void kernel_launch(void* const* d_in, const int* in_sizes, int n_in,
                              void* d_out, int out_size, void* d_ws, size_t ws_size,
                              hipStream_t stream) {
    const float* pconf   = (const float*)d_in[0];
    const float* pcls    = (const float*)d_in[1];
    const float* ptxywh  = (const float*)d_in[2];
    const float* gboxes  = (const float*)d_in[3];
    const int*   glabels = (const int*)d_in[4];
    float* out = (float*)d_out;
    float* partial = (float*)d_ws;

    yolo_loss_batch<<<BB, NTH, 0, stream>>>(pconf, pcls, ptxywh, gboxes, glabels, partial);
    yolo_loss_reduce<<<1, 256, 0, stream>>>(partial, out);
}

// Round 13
// 24.970 us; speedup vs baseline: 1.1008x; 1.0327x over previous
//
#include <hip/hip_runtime.h>
#include <hip/hip_bf16.h>

#define BB 256
#define NGT 8
#define HWA 10647
#define NTH 1024
#define NREG 11          // ceil(HWA/NTH)
#define CAP 1024
#define NAB 96           // above-boundary count < k <= 72
#define HC 4             // histogram copies (salted by wave&3)
#define HP 264           // copy stride in ints: 264%32==8 -> copies bank-offset
#define EPSF 1e-6f
#define FP16_EPS 0.0009765625f

// exact reference value: -log1p(-clip(sigmoid(x)))
__device__ __forceinline__ float lv_exact(float x) {
    float s = 1.f / (1.f + expf(-x));
    s = fminf(fmaxf(s, EPSF), 1.f - EPSF);
    return -log1pf(-s);
}
// order-monotone unsigned key for float compare
__device__ __forceinline__ unsigned fkey(float x) {
    const unsigned u = __float_as_uint(x);
    return u ^ ((u & 0x80000000u) ? 0xFFFFFFFFu : 0x80000000u);
}

__global__ __launch_bounds__(NTH) void yolo_loss_batch(
    const float* __restrict__ pconf, const float* __restrict__ pcls,
    const float* __restrict__ ptxywh, const float* __restrict__ gboxes,
    const int* __restrict__ glabels, float* __restrict__ partial)
{
    const int b = blockIdx.x;
    const int tid = threadIdx.x;
    const int lane = tid & 63;
    const int wv = tid >> 6;

    __shared__ int   hist[HC][HP];
    __shared__ int   hist2[256];
    __shared__ __align__(16) float cand[CAP];
    __shared__ float sab[NAB];
    __shared__ int   s_idx[NGT];
    __shared__ float s_row[NGT][13];
    __shared__ int   s_npos, s_ccount, s_nab;
    __shared__ float fred[16];

    // ---- issue all global loads early ----
    float gl = 0.f, gt = 0.f, gr = 0.f, gbo = 0.f;
    int lab = 0;
    if (tid < NGT) {
        const float* gb = gboxes + ((size_t)b * NGT + tid) * 4;
        gl = gb[0]; gt = gb[1]; gr = gb[2]; gbo = gb[3];
        lab = glabels[b * NGT + tid] - 1;
    }
    const float* pc = pconf + (size_t)b * HWA;
    float x[NREG];
#pragma unroll
    for (int v = 0; v < NREG; ++v) {
        const int p = tid + v * NTH;
        x[v] = (p < HWA) ? pc[p] : 0.f;
    }
    for (int i = tid; i < HC * HP; i += NTH) ((int*)hist)[i] = 0;
    if (tid < 256) hist2[tid] = 0;
    if (tid == 0)  { s_npos = 0; s_ccount = 0; s_nab = 0; }

    // ---- Phase A: per-GT matching (threads 0..7) ----
    if (tid < NGT) {
        const float cx = (gl + gr) * 0.5f, cy = (gt + gbo) * 0.5f;
        const float w = gr - gl, h = gbo - gt;
        const float area_g = w * h;
        const float AW[9] = {0.0276f, 0.0386f, 0.0795f, 0.0721f, 0.1495f, 0.1421f, 0.2788f, 0.375f, 0.897f};
        const float AH[9] = {0.0361f, 0.0697f, 0.0553f, 0.1466f, 0.1087f, 0.2861f, 0.2163f, 0.476f, 0.784f};
        float best = -1.f, baw = AW[0], bah = AH[0];
        int id = 0;
#pragma unroll
        for (int a = 0; a < 9; ++a) {
            float inter = fminf(w, AW[a]) * fminf(h, AH[a]);
            float iou = inter / (area_g + AW[a] * AH[a] - inter);
            if (iou > best) { best = iou; id = a; baw = AW[a]; bah = AH[a]; }
        }
        const int ceng = id / 3, anc = id % 3;
        const int grid = (ceng == 0) ? 52 : ((ceng == 1) ? 26 : 13);
        const int coff = (ceng == 0) ? 0 : ((ceng == 1) ? 8112 : 10140);
        const float gf = (float)grid;
        const int col = (int)(cx * gf);
        const int row = (int)(cy * gf);
        s_idx[tid] = coff + (row * grid + col) * 3 + anc;
        float* rr = s_row[tid];
        rr[0] = 1.f;
        rr[1] = (lab == 0) ? 1.f : 0.f;
        rr[2] = (lab == 1) ? 1.f : 0.f;
        rr[3] = (lab == 2) ? 1.f : 0.f;
        rr[4] = (cx - (float)col / gf) * gf;
        rr[5] = (cy - (float)row / gf) * gf;
        rr[6] = logf(w / baw);
        rr[7] = logf(h / bah);
        rr[8] = 2.f - area_g;
        rr[9] = gl; rr[10] = gt; rr[11] = gr; rr[12] = gbo;
    }
    __syncthreads();   // B1: s_idx/s_row ready, hists zeroed

    // hoist match indices to registers (broadcast LDS reads)
    int idxr[NGT];
#pragma unroll
    for (int j = 0; j < NGT; ++j) idxr[j] = s_idx[j];

    float psum = 0.f;  // this thread's share of every loss term

    // ---- Phase A2: scatter replay on threads 0..23 (loss deferred to end) ----
    int myconf = 0, mysrc = -1, myp = -1; bool canon = false;
    if (tid < 3 * NGT) {
        const int i = tid / 3, d = tid % 3;
        const int p = idxr[i] + d;
        if (p < HWA) {                    // OOB scatter dropped by JAX
            myp = p;
            canon = true;
            for (int c2 = 0; c2 < tid; ++c2)
                if (idxr[c2 / 3] + (c2 % 3) == p) { canon = false; break; }
#pragma unroll
            for (int j = 0; j < NGT; ++j) {
                const int dj = p - idxr[j];
                if (dj >= 0 && dj < 3) myconf = -1;     // ignore-mark col0
                if (dj == 0) { myconf = 1; mysrc = j; } // full-row set
            }
            if (canon && myconf == 1) atomicAdd(&s_npos, 1);
        }
    }

    // ---- Phase B: mask (incremental compare) + salted key histogram ----
    int cj[NGT];
#pragma unroll
    for (int j = 0; j < NGT; ++j) cj[j] = tid - idxr[j];
    unsigned mmask = 0;
#pragma unroll
    for (int v = 0; v < NREG; ++v) {
        const int p = tid + v * NTH;
        bool m = (p >= HWA);
#pragma unroll
        for (int j = 0; j < NGT; ++j) m = m || ((unsigned)cj[j] < 3u);
        if (m) mmask |= (1u << v);
        else atomicAdd(&hist[wv & (HC - 1)][fkey(x[v]) >> 24], 1);
#pragma unroll
        for (int j = 0; j < NGT; ++j) cj[j] += NTH;
    }
    __syncthreads();   // B2: hist + npos final

    const int npos = s_npos;
    const float nums_pos = fmaxf((float)npos, FP16_EPS);
    const int k = (npos > 0) ? (3 * npos) : 1;

    // ---- boundary-byte search: replicated per-wave suffix scan (no barriers) ----
    int bStar, above1, cbin;
    {
        int h0 = 0, h1 = 0, h2 = 0, h3 = 0;
#pragma unroll
        for (int c = 0; c < HC; ++c) {
            h0 += hist[c][4 * lane + 0]; h1 += hist[c][4 * lane + 1];
            h2 += hist[c][4 * lane + 2]; h3 += hist[c][4 * lane + 3];
        }
        const int s3 = h3, s2 = h2 + s3, s1 = h1 + s2, s0 = h0 + s1;
        int t = s0;
#pragma unroll
        for (int off = 1; off < 64; off <<= 1) {
            const int o = __shfl_down(t, off, 64);
            t += (lane + off < 64) ? o : 0;
        }
        const int aw = t - s0;              // count in lanes > lane
        int fbin = 0, fsa = 0, fcb = 0;
        bool found = false;
        const int a0 = aw + s1, a1 = aw + s2, a2 = aw + s3, a3 = aw;
        if (a0 < k && a0 + h0 >= k) { fbin = 4 * lane + 0; fsa = a0; fcb = h0; found = true; }
        if (a1 < k && a1 + h1 >= k) { fbin = 4 * lane + 1; fsa = a1; fcb = h1; found = true; }
        if (a2 < k && a2 + h2 >= k) { fbin = 4 * lane + 2; fsa = a2; fcb = h2; found = true; }
        if (a3 < k && a3 + h3 >= k) { fbin = 4 * lane + 3; fsa = a3; fcb = h3; found = true; }
        const unsigned long long bm = __ballot(found);
        const int src = __ffsll(bm) - 1;
        bStar  = __shfl(fbin, src, 64);
        above1 = __shfl(fsa,  src, 64);
        cbin   = __shfl(fcb,  src, 64);
    }
    const bool fits = (cbin <= CAP);

    // ---- gather above-boundary + boundary-bin from registers ----
#pragma unroll
    for (int v = 0; v < NREG; ++v) {
        if (!(mmask & (1u << v))) {
            const unsigned kb = fkey(x[v]) >> 24;
            if ((int)kb > bStar) {
                const int i = atomicAdd(&s_nab, 1);
                sab[i] = x[v];
            } else if ((int)kb == bStar) {
                if (fits) { const int c = atomicAdd(&s_ccount, 1); cand[c] = x[v]; }
                else atomicAdd(&hist2[(fkey(x[v]) >> 16) & 0xff], 1);
            }
        }
    }
    __syncthreads();   // B5: sab/cand (or hist2) ready

    // compacted libm for above-boundary values
    for (int t = tid; t < s_nab; t += NTH) psum += lv_exact(sab[t]);

    int rneed;
    if (fits) {
        rneed = k - above1;
    } else {
        // rare fallback: refine by next 8 key bits (replicated wave scan)
        int mStar, aboveF;
        {
            const int h0 = hist2[4 * lane + 0], h1 = hist2[4 * lane + 1];
            const int h2 = hist2[4 * lane + 2], h3 = hist2[4 * lane + 3];
            const int s3 = h3, s2 = h2 + s3, s1 = h1 + s2, s0 = h0 + s1;
            int t = s0;
#pragma unroll
            for (int off = 1; off < 64; off <<= 1) {
                const int o = __shfl_down(t, off, 64);
                t += (lane + off < 64) ? o : 0;
            }
            const int aw = t - s0;
            int fbin = 0, fsa = 0;
            bool found = false;
            const int a0 = above1 + aw + s1, a1 = above1 + aw + s2;
            const int a2 = above1 + aw + s3, a3 = above1 + aw;
            if (a0 < k && a0 + h0 >= k) { fbin = 4 * lane + 0; fsa = a0; found = true; }
            if (a1 < k && a1 + h1 >= k) { fbin = 4 * lane + 1; fsa = a1; found = true; }
            if (a2 < k && a2 + h2 >= k) { fbin = 4 * lane + 2; fsa = a2; found = true; }
            if (a3 < k && a3 + h3 >= k) { fbin = 4 * lane + 3; fsa = a3; found = true; }
            const unsigned long long bm = __ballot(found);
            const int src = __ffsll(bm) - 1;
            mStar  = __shfl(fbin, src, 64);
            aboveF = __shfl(fsa,  src, 64);
        }
#pragma unroll
        for (int v = 0; v < NREG; ++v) {
            if (!(mmask & (1u << v))) {
                const unsigned kk = fkey(x[v]);
                if ((int)(kk >> 24) == bStar) {
                    const int mb = (int)((kk >> 16) & 0xff);
                    if (mb > mStar) psum += lv_exact(x[v]);
                    else if (mb == mStar) {
                        const int c = atomicAdd(&s_ccount, 1);
                        if (c < CAP) cand[c] = x[v];
                    }
                }
            }
        }
        __syncthreads();
        rneed = k - aboveF;
    }

    // ---- one-shot rank select over boundary candidates (float4 LDS reads) ----
    const int C = min(s_ccount, CAP);
    const int C4 = C & ~3;
    for (int t = tid; t < C; t += NTH) {
        const float v = cand[t];
        int rank = 0;
        for (int j = 0; j < C4; j += 4) {
            const float4 w4 = *reinterpret_cast<const float4*>(&cand[j]);
            rank += (w4.x > v) || (w4.x == v && (j + 0) < t);
            rank += (w4.y > v) || (w4.y == v && (j + 1) < t);
            rank += (w4.z > v) || (w4.z == v && (j + 2) < t);
            rank += (w4.w > v) || (w4.w == v && (j + 3) < t);
        }
        for (int j = C4; j < C; ++j) {
            const float w = cand[j];
            rank += (w > v) || (w == v && j < t);
        }
        if (rank < rneed) psum += lv_exact(v);
    }

    // ---- Phase D (deferred): positive-position terms, overlaps rank-select ----
    if (canon && myconf == 1) {
        const float* rr = s_row[mysrc];
        const int p = myp;
        float acc = -logf(fminf(fmaxf(1.f / (1.f + expf(-pc[p])), EPSF), 1.f - EPSF));
        const float* pcl = pcls + ((size_t)b * HWA + p) * 3;
#pragma unroll
        for (int cc = 0; cc < 3; ++cc) {
            const float sc = fminf(fmaxf(1.f / (1.f + expf(-pcl[cc])), EPSF), 1.f - EPSF);
            const float g = rr[1 + cc];
            acc += -(g * logf(sc) + (1.f - g) * log1pf(-sc));
        }
        const float* pt = ptxywh + ((size_t)b * HWA + p) * 4;
        const float wgt = rr[8];
        float a2 = 0.f;
#pragma unroll
        for (int cc = 0; cc < 2; ++cc) {
            const float st = fminf(fmaxf(1.f / (1.f + expf(-pt[cc])), EPSF), 1.f - EPSF);
            const float g = rr[4 + cc];
            a2 += -(g * logf(st) + (1.f - g) * log1pf(-st));
        }
        acc += a2 * wgt;
        const float d0 = pt[2] - rr[6], d1 = pt[3] - rr[7];
        acc += (d0 * d0 + d1 * d1) * wgt;
        psum += acc;
    }

    // ---- deterministic block reduction ----
    {
        float v = psum;
#pragma unroll
        for (int off = 32; off > 0; off >>= 1) v += __shfl_down(v, off, 64);
        if (lane == 0) fred[wv] = v;
    }
    __syncthreads();
    if (tid == 0) {
        float t = 0.f;
#pragma unroll
        for (int w = 0; w < 16; ++w) t += fred[w];
        partial[b] = t / nums_pos;
    }
}

__global__ __launch_bounds__(256) void yolo_loss_reduce(
    const float* __restrict__ partial, float* __restrict__ out)
{
    const int tid = threadIdx.x;
    float v = partial[tid];
#pragma unroll
    for (int off = 32; off > 0; off >>= 1) v += __shfl_down(v, off, 64);
    __shared__ float s[4];
    if ((tid & 63) == 0) s[tid >> 6] = v;
    __syncthreads();
    if (tid == 0) out[0] = (s[0] + s[1] + s[2] + s[3]) * (1.f / (float)BB);
}

extern "C" void kernel_launch(void* const* d_in, const int* in_sizes, int n_in,
                              void* d_out, int out_size, void* d_ws, size_t ws_size,
                              hipStream_t stream) {
    const float* pconf   = (const float*)d_in[0];
    const float* pcls    = (const float*)d_in[1];
    const float* ptxywh  = (const float*)d_in[2];
    const float* gboxes  = (const float*)d_in[3];
    const int*   glabels = (const int*)d_in[4];
    float* out = (float*)d_out;
    float* partial = (float*)d_ws;

    yolo_loss_batch<<<BB, NTH, 0, stream>>>(pconf, pcls, ptxywh, gboxes, glabels, partial);
    yolo_loss_reduce<<<1, 256, 0, stream>>>(partial, out);
}

// Round 14
// 24.964 us; speedup vs baseline: 1.1010x; 1.0002x over previous
//
#include <hip/hip_runtime.h>
#include <hip/hip_bf16.h>

#define BB 256
#define NGT 8
#define HWA 10647
#define NTH 1024
#define NREG 11          // ceil(HWA/NTH)
#define CAP 1024
#define NAB 96           // above-boundary count < k <= 72
#define HC 4             // histogram copies (salted by wave&3)
#define HP 264           // copy stride in ints: 264%32==8 -> copies bank-offset
#define EPSF 1e-6f
#define FP16_EPS 0.0009765625f

// exact reference value: -log1p(-clip(sigmoid(x)))
__device__ __forceinline__ float lv_exact(float x) {
    float s = 1.f / (1.f + expf(-x));
    s = fminf(fmaxf(s, EPSF), 1.f - EPSF);
    return -log1pf(-s);
}
// order-monotone unsigned key for float compare
__device__ __forceinline__ unsigned fkey(float x) {
    const unsigned u = __float_as_uint(x);
    return u ^ ((u & 0x80000000u) ? 0xFFFFFFFFu : 0x80000000u);
}

__global__ __launch_bounds__(NTH) void yolo_loss_batch(
    const float* __restrict__ pconf, const float* __restrict__ pcls,
    const float* __restrict__ ptxywh, const float* __restrict__ gboxes,
    const int* __restrict__ glabels, float* __restrict__ partial)
{
    const int b = blockIdx.x;
    const int tid = threadIdx.x;
    const int lane = tid & 63;
    const int wv = tid >> 6;

    __shared__ int   hist[HC][HP];
    __shared__ int   hist2[256];
    __shared__ __align__(16) float cand[CAP];
    __shared__ float sab[NAB];
    __shared__ int   s_idx[NGT];
    __shared__ float s_row[NGT][13];
    __shared__ int   s_npos, s_ccount, s_nab;
    __shared__ float fred[16];

    // ---- issue all global loads early ----
    float gl = 0.f, gt = 0.f, gr = 0.f, gbo = 0.f;
    int lab = 0;
    if (tid < NGT) {
        const float* gb = gboxes + ((size_t)b * NGT + tid) * 4;
        gl = gb[0]; gt = gb[1]; gr = gb[2]; gbo = gb[3];
        lab = glabels[b * NGT + tid] - 1;
    }
    const float* pc = pconf + (size_t)b * HWA;
    float x[NREG];
#pragma unroll
    for (int v = 0; v < NREG; ++v) {
        const int p = tid + v * NTH;
        x[v] = (p < HWA) ? pc[p] : 0.f;
    }
    for (int i = tid; i < HC * HP; i += NTH) ((int*)hist)[i] = 0;
    if (tid < 256) hist2[tid] = 0;
    if (tid == 0)  { s_npos = 0; s_ccount = 0; s_nab = 0; }

    // ---- Phase A: per-GT matching (threads 0..7) ----
    if (tid < NGT) {
        const float cx = (gl + gr) * 0.5f, cy = (gt + gbo) * 0.5f;
        const float w = gr - gl, h = gbo - gt;
        const float area_g = w * h;
        const float AW[9] = {0.0276f, 0.0386f, 0.0795f, 0.0721f, 0.1495f, 0.1421f, 0.2788f, 0.375f, 0.897f};
        const float AH[9] = {0.0361f, 0.0697f, 0.0553f, 0.1466f, 0.1087f, 0.2861f, 0.2163f, 0.476f, 0.784f};
        float best = -1.f, baw = AW[0], bah = AH[0];
        int id = 0;
#pragma unroll
        for (int a = 0; a < 9; ++a) {
            float inter = fminf(w, AW[a]) * fminf(h, AH[a]);
            float iou = inter / (area_g + AW[a] * AH[a] - inter);
            if (iou > best) { best = iou; id = a; baw = AW[a]; bah = AH[a]; }
        }
        const int ceng = id / 3, anc = id % 3;
        const int grid = (ceng == 0) ? 52 : ((ceng == 1) ? 26 : 13);
        const int coff = (ceng == 0) ? 0 : ((ceng == 1) ? 8112 : 10140);
        const float gf = (float)grid;
        const int col = (int)(cx * gf);
        const int row = (int)(cy * gf);
        s_idx[tid] = coff + (row * grid + col) * 3 + anc;
        float* rr = s_row[tid];
        rr[0] = 1.f;
        rr[1] = (lab == 0) ? 1.f : 0.f;
        rr[2] = (lab == 1) ? 1.f : 0.f;
        rr[3] = (lab == 2) ? 1.f : 0.f;
        rr[4] = (cx - (float)col / gf) * gf;
        rr[5] = (cy - (float)row / gf) * gf;
        rr[6] = logf(w / baw);
        rr[7] = logf(h / bah);
        rr[8] = 2.f - area_g;
        rr[9] = gl; rr[10] = gt; rr[11] = gr; rr[12] = gbo;
    }
    __syncthreads();   // B1: s_idx/s_row ready, hists zeroed

    // hoist match indices to registers (broadcast LDS reads)
    int idxr[NGT];
#pragma unroll
    for (int j = 0; j < NGT; ++j) idxr[j] = s_idx[j];

    float psum = 0.f;  // this thread's share of every loss term

    // ---- Phase A2: scatter replay on threads 0..23 (loss deferred to end) ----
    int myconf = 0, mysrc = -1, myp = -1; bool canon = false;
    if (tid < 3 * NGT) {
        const int i = tid / 3, d = tid % 3;
        const int p = idxr[i] + d;
        if (p < HWA) {                    // OOB scatter dropped by JAX
            myp = p;
            canon = true;
            for (int c2 = 0; c2 < tid; ++c2)
                if (idxr[c2 / 3] + (c2 % 3) == p) { canon = false; break; }
#pragma unroll
            for (int j = 0; j < NGT; ++j) {
                const int dj = p - idxr[j];
                if (dj >= 0 && dj < 3) myconf = -1;     // ignore-mark col0
                if (dj == 0) { myconf = 1; mysrc = j; } // full-row set
            }
            if (canon && myconf == 1) atomicAdd(&s_npos, 1);
        }
    }

    // ---- Phase D prefetch: issue positive-position loads NOW (latency hides
    //      under Phase B + scan + gather + rank-select; compute at the end) ----
    float dxp = 0.f, dcl0 = 0.f, dcl1 = 0.f, dcl2 = 0.f;
    float dpt0 = 0.f, dpt1 = 0.f, dpt2 = 0.f, dpt3 = 0.f;
    const bool dpos = canon && (myconf == 1);
    if (dpos) {
        const int p = myp;
        dxp = pc[p];
        const float* pcl = pcls + ((size_t)b * HWA + p) * 3;
        dcl0 = pcl[0]; dcl1 = pcl[1]; dcl2 = pcl[2];
        const float* pt = ptxywh + ((size_t)b * HWA + p) * 4;
        dpt0 = pt[0]; dpt1 = pt[1]; dpt2 = pt[2]; dpt3 = pt[3];
    }

    // ---- Phase B: mask (incremental compare) + salted key histogram ----
    int cj[NGT];
#pragma unroll
    for (int j = 0; j < NGT; ++j) cj[j] = tid - idxr[j];
    unsigned mmask = 0;
#pragma unroll
    for (int v = 0; v < NREG; ++v) {
        const int p = tid + v * NTH;
        bool m = (p >= HWA);
#pragma unroll
        for (int j = 0; j < NGT; ++j) m = m || ((unsigned)cj[j] < 3u);
        if (m) mmask |= (1u << v);
        else atomicAdd(&hist[wv & (HC - 1)][fkey(x[v]) >> 24], 1);
#pragma unroll
        for (int j = 0; j < NGT; ++j) cj[j] += NTH;
    }
    __syncthreads();   // B2: hist + npos final

    const int npos = s_npos;
    const float nums_pos = fmaxf((float)npos, FP16_EPS);
    const int k = (npos > 0) ? (3 * npos) : 1;

    // ---- boundary-byte search: replicated per-wave suffix scan (no barriers) ----
    int bStar, above1, cbin;
    {
        int h0 = 0, h1 = 0, h2 = 0, h3 = 0;
#pragma unroll
        for (int c = 0; c < HC; ++c) {
            h0 += hist[c][4 * lane + 0]; h1 += hist[c][4 * lane + 1];
            h2 += hist[c][4 * lane + 2]; h3 += hist[c][4 * lane + 3];
        }
        const int s3 = h3, s2 = h2 + s3, s1 = h1 + s2, s0 = h0 + s1;
        int t = s0;
#pragma unroll
        for (int off = 1; off < 64; off <<= 1) {
            const int o = __shfl_down(t, off, 64);
            t += (lane + off < 64) ? o : 0;
        }
        const int aw = t - s0;              // count in lanes > lane
        int fbin = 0, fsa = 0, fcb = 0;
        bool found = false;
        const int a0 = aw + s1, a1 = aw + s2, a2 = aw + s3, a3 = aw;
        if (a0 < k && a0 + h0 >= k) { fbin = 4 * lane + 0; fsa = a0; fcb = h0; found = true; }
        if (a1 < k && a1 + h1 >= k) { fbin = 4 * lane + 1; fsa = a1; fcb = h1; found = true; }
        if (a2 < k && a2 + h2 >= k) { fbin = 4 * lane + 2; fsa = a2; fcb = h2; found = true; }
        if (a3 < k && a3 + h3 >= k) { fbin = 4 * lane + 3; fsa = a3; fcb = h3; found = true; }
        const unsigned long long bm = __ballot(found);
        const int src = __ffsll(bm) - 1;
        bStar  = __shfl(fbin, src, 64);
        above1 = __shfl(fsa,  src, 64);
        cbin   = __shfl(fcb,  src, 64);
    }
    const bool fits = (cbin <= CAP);

    // ---- gather above-boundary + boundary-bin from registers ----
#pragma unroll
    for (int v = 0; v < NREG; ++v) {
        if (!(mmask & (1u << v))) {
            const unsigned kb = fkey(x[v]) >> 24;
            if ((int)kb > bStar) {
                const int i = atomicAdd(&s_nab, 1);
                sab[i] = x[v];
            } else if ((int)kb == bStar) {
                if (fits) { const int c = atomicAdd(&s_ccount, 1); cand[c] = x[v]; }
                else atomicAdd(&hist2[(fkey(x[v]) >> 16) & 0xff], 1);
            }
        }
    }
    __syncthreads();   // B5: sab/cand (or hist2) ready

    // compacted libm for above-boundary values
    for (int t = tid; t < s_nab; t += NTH) psum += lv_exact(sab[t]);

    int rneed;
    if (fits) {
        rneed = k - above1;
    } else {
        // rare fallback: refine by next 8 key bits (replicated wave scan)
        int mStar, aboveF;
        {
            const int h0 = hist2[4 * lane + 0], h1 = hist2[4 * lane + 1];
            const int h2 = hist2[4 * lane + 2], h3 = hist2[4 * lane + 3];
            const int s3 = h3, s2 = h2 + s3, s1 = h1 + s2, s0 = h0 + s1;
            int t = s0;
#pragma unroll
            for (int off = 1; off < 64; off <<= 1) {
                const int o = __shfl_down(t, off, 64);
                t += (lane + off < 64) ? o : 0;
            }
            const int aw = t - s0;
            int fbin = 0, fsa = 0;
            bool found = false;
            const int a0 = above1 + aw + s1, a1 = above1 + aw + s2;
            const int a2 = above1 + aw + s3, a3 = above1 + aw;
            if (a0 < k && a0 + h0 >= k) { fbin = 4 * lane + 0; fsa = a0; found = true; }
            if (a1 < k && a1 + h1 >= k) { fbin = 4 * lane + 1; fsa = a1; found = true; }
            if (a2 < k && a2 + h2 >= k) { fbin = 4 * lane + 2; fsa = a2; found = true; }
            if (a3 < k && a3 + h3 >= k) { fbin = 4 * lane + 3; fsa = a3; found = true; }
            const unsigned long long bm = __ballot(found);
            const int src = __ffsll(bm) - 1;
            mStar  = __shfl(fbin, src, 64);
            aboveF = __shfl(fsa,  src, 64);
        }
#pragma unroll
        for (int v = 0; v < NREG; ++v) {
            if (!(mmask & (1u << v))) {
                const unsigned kk = fkey(x[v]);
                if ((int)(kk >> 24) == bStar) {
                    const int mb = (int)((kk >> 16) & 0xff);
                    if (mb > mStar) psum += lv_exact(x[v]);
                    else if (mb == mStar) {
                        const int c = atomicAdd(&s_ccount, 1);
                        if (c < CAP) cand[c] = x[v];
                    }
                }
            }
        }
        __syncthreads();
        rneed = k - aboveF;
    }

    // ---- one-shot rank select over boundary candidates (float4 LDS reads) ----
    const int C = min(s_ccount, CAP);
    const int C4 = C & ~3;
    for (int t = tid; t < C; t += NTH) {
        const float v = cand[t];
        int rank = 0;
        for (int j = 0; j < C4; j += 4) {
            const float4 w4 = *reinterpret_cast<const float4*>(&cand[j]);
            rank += (w4.x > v) || (w4.x == v && (j + 0) < t);
            rank += (w4.y > v) || (w4.y == v && (j + 1) < t);
            rank += (w4.z > v) || (w4.z == v && (j + 2) < t);
            rank += (w4.w > v) || (w4.w == v && (j + 3) < t);
        }
        for (int j = C4; j < C; ++j) {
            const float w = cand[j];
            rank += (w > v) || (w == v && j < t);
        }
        if (rank < rneed) psum += lv_exact(v);
    }

    // ---- Phase D (deferred compute from prefetched registers) ----
    if (dpos) {
        const float* rr = s_row[mysrc];
        float acc = -logf(fminf(fmaxf(1.f / (1.f + expf(-dxp)), EPSF), 1.f - EPSF));
        const float cl[3] = { dcl0, dcl1, dcl2 };
#pragma unroll
        for (int cc = 0; cc < 3; ++cc) {
            const float sc = fminf(fmaxf(1.f / (1.f + expf(-cl[cc])), EPSF), 1.f - EPSF);
            const float g = rr[1 + cc];
            acc += -(g * logf(sc) + (1.f - g) * log1pf(-sc));
        }
        const float wgt = rr[8];
        const float tt[2] = { dpt0, dpt1 };
        float a2 = 0.f;
#pragma unroll
        for (int cc = 0; cc < 2; ++cc) {
            const float st = fminf(fmaxf(1.f / (1.f + expf(-tt[cc])), EPSF), 1.f - EPSF);
            const float g = rr[4 + cc];
            a2 += -(g * logf(st) + (1.f - g) * log1pf(-st));
        }
        acc += a2 * wgt;
        const float d0 = dpt2 - rr[6], d1 = dpt3 - rr[7];
        acc += (d0 * d0 + d1 * d1) * wgt;
        psum += acc;
    }

    // ---- deterministic block reduction ----
    {
        float v = psum;
#pragma unroll
        for (int off = 32; off > 0; off >>= 1) v += __shfl_down(v, off, 64);
        if (lane == 0) fred[wv] = v;
    }
    __syncthreads();
    if (tid == 0) {
        float t = 0.f;
#pragma unroll
        for (int w = 0; w < 16; ++w) t += fred[w];
        partial[b] = t / nums_pos;
    }
}

__global__ __launch_bounds__(256) void yolo_loss_reduce(
    const float* __restrict__ partial, float* __restrict__ out)
{
    const int tid = threadIdx.x;
    float v = partial[tid];
#pragma unroll
    for (int off = 32; off > 0; off >>= 1) v += __shfl_down(v, off, 64);
    __shared__ float s[4];
    if ((tid & 63) == 0) s[tid >> 6] = v;
    __syncthreads();
    if (tid == 0) out[0] = (s[0] + s[1] + s[2] + s[3]) * (1.f / (float)BB);
}

extern "C" void kernel_launch(void* const* d_in, const int* in_sizes, int n_in,
                              void* d_out, int out_size, void* d_ws, size_t ws_size,
                              hipStream_t stream) {
    const float* pconf   = (const float*)d_in[0];
    const float* pcls    = (const float*)d_in[1];
    const float* ptxywh  = (const float*)d_in[2];
    const float* gboxes  = (const float*)d_in[3];
    const int*   glabels = (const int*)d_in[4];
    float* out = (float*)d_out;
    float* partial = (float*)d_ws;

    yolo_loss_batch<<<BB, NTH, 0, stream>>>(pconf, pcls, ptxywh, gboxes, glabels, partial);
    yolo_loss_reduce<<<1, 256, 0, stream>>>(partial, out);
}

// Round 15
// 24.745 us; speedup vs baseline: 1.1108x; 1.0089x over previous
//
#include <hip/hip_runtime.h>
#include <hip/hip_bf16.h>

#define BB 256
#define NGT 8
#define HWA 10647
#define NTH 1024
#define NQ 4             // elements per quad
#define NQR 3            // quads per thread: 3*4*1024 = 12288 >= HWA
#define CAP 1024
#define NAB 96           // above-boundary count < k <= 72
#define HC 4             // histogram copies (salted by wave&3)
#define HP 264           // copy stride in ints: 264%32==8 -> copies bank-offset
#define EPSF 1e-6f
#define FP16_EPS 0.0009765625f

// exact reference value: -log1p(-clip(sigmoid(x)))
__device__ __forceinline__ float lv_exact(float x) {
    float s = 1.f / (1.f + expf(-x));
    s = fminf(fmaxf(s, EPSF), 1.f - EPSF);
    return -log1pf(-s);
}
// order-monotone unsigned key for float compare
__device__ __forceinline__ unsigned fkey(float x) {
    const unsigned u = __float_as_uint(x);
    return u ^ ((u & 0x80000000u) ? 0xFFFFFFFFu : 0x80000000u);
}

__global__ __launch_bounds__(NTH) void yolo_loss_batch(
    const float* __restrict__ pconf, const float* __restrict__ pcls,
    const float* __restrict__ ptxywh, const float* __restrict__ gboxes,
    const int* __restrict__ glabels, float* __restrict__ partial)
{
    const int b = blockIdx.x;
    const int tid = threadIdx.x;
    const int lane = tid & 63;
    const int wv = tid >> 6;

    __shared__ int   hist[HC][HP];
    __shared__ int   hist2[256];
    __shared__ __align__(16) float cand[CAP];
    __shared__ float sab[NAB];
    __shared__ int   s_idx[NGT];
    __shared__ float s_row[NGT][13];
    __shared__ int   s_npos, s_ccount, s_nab;
    __shared__ float fred[16];

    // ---- issue all global loads early: aligned float4 quads + pad prologue ----
    float gl = 0.f, gt = 0.f, gr = 0.f, gbo = 0.f;
    int lab = 0;
    if (tid < NGT) {
        const float* gb = gboxes + ((size_t)b * NGT + tid) * 4;
        gl = gb[0]; gt = gb[1]; gr = gb[2]; gbo = gb[3];
        lab = glabels[b * NGT + tid] - 1;
    }
    const float* pc = pconf + (size_t)b * HWA;
    const int pad = (int)((16u - ((unsigned)(uintptr_t)pc & 15u)) & 15u) >> 2; // 0..3
    const float* pca = pc + pad;                 // 16B-aligned
    float4 xq[NQR];
#pragma unroll
    for (int q = 0; q < NQR; ++q) {
        const int pb = 4 * (tid + q * NTH);      // element index rel. to pca
        const int p0 = pad + pb;                 // absolute element index
        if (p0 + 3 < HWA) {
            xq[q] = *reinterpret_cast<const float4*>(pca + pb);
        } else {
            float4 t = make_float4(0.f, 0.f, 0.f, 0.f);
            if (p0 + 0 < HWA) t.x = pca[pb + 0];
            if (p0 + 1 < HWA) t.y = pca[pb + 1];
            if (p0 + 2 < HWA) t.z = pca[pb + 2];
            if (p0 + 3 < HWA) t.w = pca[pb + 3];
            xq[q] = t;
        }
    }
    const float xpre = (tid < pad) ? pc[tid] : 0.f;   // leading unaligned floats
    for (int i = tid; i < HC * HP; i += NTH) ((int*)hist)[i] = 0;
    if (tid < 256) hist2[tid] = 0;
    if (tid == 0)  { s_npos = 0; s_ccount = 0; s_nab = 0; }

    // ---- Phase A: per-GT matching (threads 0..7) ----
    if (tid < NGT) {
        const float cx = (gl + gr) * 0.5f, cy = (gt + gbo) * 0.5f;
        const float w = gr - gl, h = gbo - gt;
        const float area_g = w * h;
        const float AW[9] = {0.0276f, 0.0386f, 0.0795f, 0.0721f, 0.1495f, 0.1421f, 0.2788f, 0.375f, 0.897f};
        const float AH[9] = {0.0361f, 0.0697f, 0.0553f, 0.1466f, 0.1087f, 0.2861f, 0.2163f, 0.476f, 0.784f};
        float best = -1.f, baw = AW[0], bah = AH[0];
        int id = 0;
#pragma unroll
        for (int a = 0; a < 9; ++a) {
            float inter = fminf(w, AW[a]) * fminf(h, AH[a]);
            float iou = inter / (area_g + AW[a] * AH[a] - inter);
            if (iou > best) { best = iou; id = a; baw = AW[a]; bah = AH[a]; }
        }
        const int ceng = id / 3, anc = id % 3;
        const int grid = (ceng == 0) ? 52 : ((ceng == 1) ? 26 : 13);
        const int coff = (ceng == 0) ? 0 : ((ceng == 1) ? 8112 : 10140);
        const float gf = (float)grid;
        const int col = (int)(cx * gf);
        const int row = (int)(cy * gf);
        s_idx[tid] = coff + (row * grid + col) * 3 + anc;
        float* rr = s_row[tid];
        rr[0] = 1.f;
        rr[1] = (lab == 0) ? 1.f : 0.f;
        rr[2] = (lab == 1) ? 1.f : 0.f;
        rr[3] = (lab == 2) ? 1.f : 0.f;
        rr[4] = (cx - (float)col / gf) * gf;
        rr[5] = (cy - (float)row / gf) * gf;
        rr[6] = logf(w / baw);
        rr[7] = logf(h / bah);
        rr[8] = 2.f - area_g;
        rr[9] = gl; rr[10] = gt; rr[11] = gr; rr[12] = gbo;
    }
    __syncthreads();   // B1: s_idx/s_row ready, hists zeroed

    // hoist match indices to registers (broadcast LDS reads)
    int idxr[NGT];
#pragma unroll
    for (int j = 0; j < NGT; ++j) idxr[j] = s_idx[j];

    float psum = 0.f;  // this thread's share of every loss term

    // ---- Phase A2: scatter replay on threads 0..23 (loss deferred to end) ----
    int myconf = 0, mysrc = -1, myp = -1; bool canon = false;
    if (tid < 3 * NGT) {
        const int i = tid / 3, d = tid % 3;
        const int p = idxr[i] + d;
        if (p < HWA) {                    // OOB scatter dropped by JAX
            myp = p;
            canon = true;
            for (int c2 = 0; c2 < tid; ++c2)
                if (idxr[c2 / 3] + (c2 % 3) == p) { canon = false; break; }
#pragma unroll
            for (int j = 0; j < NGT; ++j) {
                const int dj = p - idxr[j];
                if (dj >= 0 && dj < 3) myconf = -1;     // ignore-mark col0
                if (dj == 0) { myconf = 1; mysrc = j; } // full-row set
            }
            if (canon && myconf == 1) atomicAdd(&s_npos, 1);
        }
    }

    // ---- Phase D prefetch (latency hides under everything below) ----
    float dxp = 0.f, dcl0 = 0.f, dcl1 = 0.f, dcl2 = 0.f;
    float dpt0 = 0.f, dpt1 = 0.f, dpt2 = 0.f, dpt3 = 0.f;
    const bool dpos = canon && (myconf == 1);
    if (dpos) {
        const int p = myp;
        dxp = pc[p];
        const float* pcl = pcls + ((size_t)b * HWA + p) * 3;
        dcl0 = pcl[0]; dcl1 = pcl[1]; dcl2 = pcl[2];
        const float* pt = ptxywh + ((size_t)b * HWA + p) * 4;
        dpt0 = pt[0]; dpt1 = pt[1]; dpt2 = pt[2]; dpt3 = pt[3];
    }

    // ---- Phase B: mask + salted key histogram (13 elements/thread) ----
    unsigned mmask = 0;   // bits 0..11 = quads, bit 12 = pre element
    {
        // pre element (p = tid, valid only when tid < pad)
        bool m = (tid >= pad);
#pragma unroll
        for (int j = 0; j < NGT; ++j) m = m || ((unsigned)(tid - idxr[j]) < 3u);
        if (m) mmask |= (1u << 12);
        else atomicAdd(&hist[wv & (HC - 1)][fkey(xpre) >> 24], 1);
    }
#pragma unroll
    for (int q = 0; q < NQR; ++q) {
        const float* xv = reinterpret_cast<const float*>(&xq[q]);
        const int pb = pad + 4 * (tid + q * NTH);
#pragma unroll
        for (int c = 0; c < NQ; ++c) {
            const int p = pb + c;
            bool m = (p >= HWA);
#pragma unroll
            for (int j = 0; j < NGT; ++j) m = m || ((unsigned)(p - idxr[j]) < 3u);
            if (m) mmask |= (1u << (q * NQ + c));
            else atomicAdd(&hist[wv & (HC - 1)][fkey(xv[c]) >> 24], 1);
        }
    }
    __syncthreads();   // B2: hist + npos final

    const int npos = s_npos;
    const float nums_pos = fmaxf((float)npos, FP16_EPS);
    const int k = (npos > 0) ? (3 * npos) : 1;

    // ---- boundary-byte search: replicated per-wave suffix scan (no barriers) ----
    int bStar, above1, cbin;
    {
        int h0 = 0, h1 = 0, h2 = 0, h3 = 0;
#pragma unroll
        for (int c = 0; c < HC; ++c) {
            h0 += hist[c][4 * lane + 0]; h1 += hist[c][4 * lane + 1];
            h2 += hist[c][4 * lane + 2]; h3 += hist[c][4 * lane + 3];
        }
        const int s3 = h3, s2 = h2 + s3, s1 = h1 + s2, s0 = h0 + s1;
        int t = s0;
#pragma unroll
        for (int off = 1; off < 64; off <<= 1) {
            const int o = __shfl_down(t, off, 64);
            t += (lane + off < 64) ? o : 0;
        }
        const int aw = t - s0;              // count in lanes > lane
        int fbin = 0, fsa = 0, fcb = 0;
        bool found = false;
        const int a0 = aw + s1, a1 = aw + s2, a2 = aw + s3, a3 = aw;
        if (a0 < k && a0 + h0 >= k) { fbin = 4 * lane + 0; fsa = a0; fcb = h0; found = true; }
        if (a1 < k && a1 + h1 >= k) { fbin = 4 * lane + 1; fsa = a1; fcb = h1; found = true; }
        if (a2 < k && a2 + h2 >= k) { fbin = 4 * lane + 2; fsa = a2; fcb = h2; found = true; }
        if (a3 < k && a3 + h3 >= k) { fbin = 4 * lane + 3; fsa = a3; fcb = h3; found = true; }
        const unsigned long long bm = __ballot(found);
        const int src = __ffsll(bm) - 1;
        bStar  = __shfl(fbin, src, 64);
        above1 = __shfl(fsa,  src, 64);
        cbin   = __shfl(fcb,  src, 64);
    }
    const bool fits = (cbin <= CAP);

    // ---- gather above-boundary + boundary-bin from registers ----
    if (!(mmask & (1u << 12))) {
        const int kb = (int)(fkey(xpre) >> 24);
        if (kb > bStar) sab[atomicAdd(&s_nab, 1)] = xpre;
        else if (kb == bStar) {
            if (fits) cand[atomicAdd(&s_ccount, 1)] = xpre;
            else atomicAdd(&hist2[(fkey(xpre) >> 16) & 0xff], 1);
        }
    }
#pragma unroll
    for (int q = 0; q < NQR; ++q) {
        const float* xv = reinterpret_cast<const float*>(&xq[q]);
#pragma unroll
        for (int c = 0; c < NQ; ++c) {
            if (!(mmask & (1u << (q * NQ + c)))) {
                const int kb = (int)(fkey(xv[c]) >> 24);
                if (kb > bStar) sab[atomicAdd(&s_nab, 1)] = xv[c];
                else if (kb == bStar) {
                    if (fits) cand[atomicAdd(&s_ccount, 1)] = xv[c];
                    else atomicAdd(&hist2[(fkey(xv[c]) >> 16) & 0xff], 1);
                }
            }
        }
    }
    __syncthreads();   // B5: sab/cand (or hist2) ready

    // compacted libm for above-boundary values
    for (int t = tid; t < s_nab; t += NTH) psum += lv_exact(sab[t]);

    int rneed;
    if (fits) {
        rneed = k - above1;
    } else {
        // rare fallback: refine by next 8 key bits (replicated wave scan)
        int mStar, aboveF;
        {
            const int h0 = hist2[4 * lane + 0], h1 = hist2[4 * lane + 1];
            const int h2 = hist2[4 * lane + 2], h3 = hist2[4 * lane + 3];
            const int s3 = h3, s2 = h2 + s3, s1 = h1 + s2, s0 = h0 + s1;
            int t = s0;
#pragma unroll
            for (int off = 1; off < 64; off <<= 1) {
                const int o = __shfl_down(t, off, 64);
                t += (lane + off < 64) ? o : 0;
            }
            const int aw = t - s0;
            int fbin = 0, fsa = 0;
            bool found = false;
            const int a0 = above1 + aw + s1, a1 = above1 + aw + s2;
            const int a2 = above1 + aw + s3, a3 = above1 + aw;
            if (a0 < k && a0 + h0 >= k) { fbin = 4 * lane + 0; fsa = a0; found = true; }
            if (a1 < k && a1 + h1 >= k) { fbin = 4 * lane + 1; fsa = a1; found = true; }
            if (a2 < k && a2 + h2 >= k) { fbin = 4 * lane + 2; fsa = a2; found = true; }
            if (a3 < k && a3 + h3 >= k) { fbin = 4 * lane + 3; fsa = a3; found = true; }
            const unsigned long long bm = __ballot(found);
            const int src = __ffsll(bm) - 1;
            mStar  = __shfl(fbin, src, 64);
            aboveF = __shfl(fsa,  src, 64);
        }
        if (!(mmask & (1u << 12))) {
            const unsigned kk = fkey(xpre);
            if ((int)(kk >> 24) == bStar) {
                const int mb = (int)((kk >> 16) & 0xff);
                if (mb > mStar) psum += lv_exact(xpre);
                else if (mb == mStar) {
                    const int c = atomicAdd(&s_ccount, 1);
                    if (c < CAP) cand[c] = xpre;
                }
            }
        }
#pragma unroll
        for (int q = 0; q < NQR; ++q) {
            const float* xv = reinterpret_cast<const float*>(&xq[q]);
#pragma unroll
            for (int c = 0; c < NQ; ++c) {
                if (!(mmask & (1u << (q * NQ + c)))) {
                    const unsigned kk = fkey(xv[c]);
                    if ((int)(kk >> 24) == bStar) {
                        const int mb = (int)((kk >> 16) & 0xff);
                        if (mb > mStar) psum += lv_exact(xv[c]);
                        else if (mb == mStar) {
                            const int cc2 = atomicAdd(&s_ccount, 1);
                            if (cc2 < CAP) cand[cc2] = xv[c];
                        }
                    }
                }
            }
        }
        __syncthreads();
        rneed = k - aboveF;
    }

    // ---- one-shot rank select over boundary candidates (float4 LDS reads) ----
    const int C = min(s_ccount, CAP);
    const int C4 = C & ~3;
    for (int t = tid; t < C; t += NTH) {
        const float v = cand[t];
        int rank = 0;
        for (int j = 0; j < C4; j += 4) {
            const float4 w4 = *reinterpret_cast<const float4*>(&cand[j]);
            rank += (w4.x > v) || (w4.x == v && (j + 0) < t);
            rank += (w4.y > v) || (w4.y == v && (j + 1) < t);
            rank += (w4.z > v) || (w4.z == v && (j + 2) < t);
            rank += (w4.w > v) || (w4.w == v && (j + 3) < t);
        }
        for (int j = C4; j < C; ++j) {
            const float w = cand[j];
            rank += (w > v) || (w == v && j < t);
        }
        if (rank < rneed) psum += lv_exact(v);
    }

    // ---- Phase D (deferred compute from prefetched registers) ----
    if (dpos) {
        const float* rr = s_row[mysrc];
        float acc = -logf(fminf(fmaxf(1.f / (1.f + expf(-dxp)), EPSF), 1.f - EPSF));
        const float cl[3] = { dcl0, dcl1, dcl2 };
#pragma unroll
        for (int cc = 0; cc < 3; ++cc) {
            const float sc = fminf(fmaxf(1.f / (1.f + expf(-cl[cc])), EPSF), 1.f - EPSF);
            const float g = rr[1 + cc];
            acc += -(g * logf(sc) + (1.f - g) * log1pf(-sc));
        }
        const float wgt = rr[8];
        const float tt[2] = { dpt0, dpt1 };
        float a2 = 0.f;
#pragma unroll
        for (int cc = 0; cc < 2; ++cc) {
            const float st = fminf(fmaxf(1.f / (1.f + expf(-tt[cc])), EPSF), 1.f - EPSF);
            const float g = rr[4 + cc];
            a2 += -(g * logf(st) + (1.f - g) * log1pf(-st));
        }
        acc += a2 * wgt;
        const float d0 = dpt2 - rr[6], d1 = dpt3 - rr[7];
        acc += (d0 * d0 + d1 * d1) * wgt;
        psum += acc;
    }

    // ---- deterministic block reduction ----
    {
        float v = psum;
#pragma unroll
        for (int off = 32; off > 0; off >>= 1) v += __shfl_down(v, off, 64);
        if (lane == 0) fred[wv] = v;
    }
    __syncthreads();
    if (tid == 0) {
        float t = 0.f;
#pragma unroll
        for (int w = 0; w < 16; ++w) t += fred[w];
        partial[b] = t / nums_pos;
    }
}

__global__ __launch_bounds__(256) void yolo_loss_reduce(
    const float* __restrict__ partial, float* __restrict__ out)
{
    const int tid = threadIdx.x;
    float v = partial[tid];
#pragma unroll
    for (int off = 32; off > 0; off >>= 1) v += __shfl_down(v, off, 64);
    __shared__ float s[4];
    if ((tid & 63) == 0) s[tid >> 6] = v;
    __syncthreads();
    if (tid == 0) out[0] = (s[0] + s[1] + s[2] + s[3]) * (1.f / (float)BB);
}

extern "C" void kernel_launch(void* const* d_in, const int* in_sizes, int n_in,
                              void* d_out, int out_size, void* d_ws, size_t ws_size,
                              hipStream_t stream) {
    const float* pconf   = (const float*)d_in[0];
    const float* pcls    = (const float*)d_in[1];
    const float* ptxywh  = (const float*)d_in[2];
    const float* gboxes  = (const float*)d_in[3];
    const int*   glabels = (const int*)d_in[4];
    float* out = (float*)d_out;
    float* partial = (float*)d_ws;

    yolo_loss_batch<<<BB, NTH, 0, stream>>>(pconf, pcls, ptxywh, gboxes, glabels, partial);
    yolo_loss_reduce<<<1, 256, 0, stream>>>(partial, out);
}